// Round 2
// baseline (561.549 us; speedup 1.0000x reference)
//
#include <hip/hip_runtime.h>
#include <hip/hip_bf16.h>

// Problem constants
#define PPIX 32768      // B*H*W = 2*128*128
#define K384 384        // C (GEMM K dim)

typedef __attribute__((ext_vector_type(8))) short s16x8;
typedef __attribute__((ext_vector_type(4))) float f32x4;

__device__ __forceinline__ float bf2f(short u) {
  union { unsigned int i; float f; } c;
  c.i = ((unsigned int)(unsigned short)u) << 16;
  return c.f;
}

__device__ __forceinline__ unsigned short f2b(float x) {
  union { float f; unsigned int i; } c; c.f = x;
  unsigned int u = c.i;
  return (unsigned short)((u + 0x7fffu + ((u >> 16) & 1u)) >> 16);  // RNE
}

// ---------------- f32 -> bf16 convert (8 elems/thread) ----------------
__global__ __launch_bounds__(256) void cvt_f32_bf16(const float* __restrict__ in,
                                                    unsigned short* __restrict__ out,
                                                    int n8) {
  int i = blockIdx.x * 256 + threadIdx.x;
  if (i >= n8) return;
  const float4* in4 = (const float4*)in;
  float4 a = in4[(size_t)i * 2], b = in4[(size_t)i * 2 + 1];
  s16x8 r;
  r[0] = (short)f2b(a.x); r[1] = (short)f2b(a.y); r[2] = (short)f2b(a.z); r[3] = (short)f2b(a.w);
  r[4] = (short)f2b(b.x); r[5] = (short)f2b(b.y); r[6] = (short)f2b(b.z); r[7] = (short)f2b(b.w);
  *(s16x8*)(out + (size_t)i * 8) = r;
}

// ---------------- bf16 MFMA GEMM: C[M,N] = A[M,K] * B[N,K]^T ----------------
// m97 structure: 128x128 tile, BK=64, 4 waves (2x2), global_load_lds width 16.
__device__ __forceinline__ void async_ld16(const void* g, void* l) {
  __builtin_amdgcn_global_load_lds(
      (const __attribute__((address_space(1))) unsigned int*)g,
      (__attribute__((address_space(3))) unsigned int*)l, 16, 0, 0);
}

template<int N, bool F32OUT>
__global__ __launch_bounds__(256) void gemm_bt(
    const unsigned short* __restrict__ A0, const unsigned short* __restrict__ A1,
    const unsigned short* __restrict__ B0, const unsigned short* __restrict__ B1,
    void* __restrict__ C0v, void* __restrict__ C1v,
    const float* __restrict__ bias0, const float* __restrict__ bias1) {
  const int bm = blockIdx.x, bn = blockIdx.y, bz = blockIdx.z;
  const unsigned short* A = bz ? A1 : A0;
  const unsigned short* Bm = bz ? B1 : B0;
  const int tid = threadIdx.x;
  const int wid = tid >> 6, lane = tid & 63;
  __shared__ unsigned short ldsA[128 * 64];
  __shared__ unsigned short ldsB[128 * 64];
  f32x4 acc[4][4] = {};
  const int wm = wid >> 1, wn = wid & 1;          // 2x2 wave grid, each wave 64x64
  const int srow = tid >> 3;                      // staging: 0..31 rows/issue
  const int scol = (tid & 7) * 8;                 // 8 bf16 (16B) per lane
  const int r = lane & 15, q2 = lane >> 4;

  for (int kt = 0; kt < K384 / 64; ++kt) {
    const int k0 = kt * 64;
#pragma unroll
    for (int j = 0; j < 4; ++j) {
      async_ld16(A + (size_t)(bm * 128 + j * 32 + srow) * K384 + k0 + scol,
                 (char*)ldsA + (j * 32 + wid * 8) * 128);
      async_ld16(Bm + (size_t)(bn * 128 + j * 32 + srow) * K384 + k0 + scol,
                 (char*)ldsB + (j * 32 + wid * 8) * 128);
    }
    __syncthreads();
#pragma unroll
    for (int ks = 0; ks < 2; ++ks) {
      s16x8 af[4], bf[4];
#pragma unroll
      for (int mi = 0; mi < 4; ++mi)
        af[mi] = *(const s16x8*)&ldsA[(wm * 64 + mi * 16 + r) * 64 + ks * 32 + q2 * 8];
#pragma unroll
      for (int ni = 0; ni < 4; ++ni)
        bf[ni] = *(const s16x8*)&ldsB[(wn * 64 + ni * 16 + r) * 64 + ks * 32 + q2 * 8];
#pragma unroll
      for (int mi = 0; mi < 4; ++mi)
#pragma unroll
        for (int ni = 0; ni < 4; ++ni)
          acc[mi][ni] = __builtin_amdgcn_mfma_f32_16x16x32_bf16(af[mi], bf[ni], acc[mi][ni], 0, 0, 0);
    }
    __syncthreads();
  }

  // Epilogue. C/D layout: col = lane&15, row = (lane>>4)*4 + reg  [m89-verified]
  if constexpr (F32OUT) {
    float* C = (float*)(bz ? C1v : C0v);
    const float* bias = bz ? bias1 : bias0;
#pragma unroll
    for (int mi = 0; mi < 4; ++mi)
#pragma unroll
      for (int ni = 0; ni < 4; ++ni) {
        const int gm = bm * 128 + wm * 64 + mi * 16 + q2 * 4;
        const int gn = bn * 128 + wn * 64 + ni * 16 + r;
        const float bv = bias[gn];
#pragma unroll
        for (int rr = 0; rr < 4; ++rr)
          C[(size_t)(gm + rr) * N + gn] = acc[mi][ni][rr] + bv;
      }
  } else {
    unsigned short* C = (unsigned short*)(bz ? C1v : C0v);
#pragma unroll
    for (int mi = 0; mi < 4; ++mi)
#pragma unroll
      for (int ni = 0; ni < 4; ++ni) {
        const int gm = bm * 128 + wm * 64 + mi * 16 + q2 * 4;
        const int gn = bn * 128 + wn * 64 + ni * 16 + r;
#pragma unroll
        for (int rr = 0; rr < 4; ++rr)
          C[(size_t)(gm + rr) * N + gn] = f2b(acc[mi][ni][rr]);
      }
  }
}

// ---------------- dilated 3x3 window attention ----------------
// 1 thread per (branch, pixel, dilation, head). qkv layout: [pix][s*384 + i*128 + h*64 + c]
// OOB taps: zero-padded gather => logit contribution 0 (NOT -inf), v tap = 0.
__global__ __launch_bounds__(256) void dilate_attn(
    const unsigned short* __restrict__ qkv_m, const unsigned short* __restrict__ qkv_f,
    unsigned short* __restrict__ att_m, unsigned short* __restrict__ att_f) {
  const int idx = blockIdx.x * 256 + threadIdx.x;   // 0 .. 393215
  const int p = idx / 6;
  const int dh = idx - p * 6;
  const int branch = p >> 15;       // 0 = mov output (q from fix, k/v from mov)
  const int pix = p & 32767;
  const int i = dh >> 1, h = dh & 1;
  const int dil = i + 1;
  const int x = pix & 127, y = (pix >> 7) & 127, b = pix >> 14;
  const unsigned short* qsrc = branch ? qkv_m : qkv_f;
  const unsigned short* kvsrc = branch ? qkv_f : qkv_m;
  unsigned short* dst = branch ? att_f : att_m;
  const int co = i * 128 + h * 64;

  // load q -> f32
  float qf[64];
  const unsigned short* qp = qsrc + (size_t)pix * 1152 + co;
#pragma unroll
  for (int j = 0; j < 8; ++j) {
    s16x8 v = *(const s16x8*)(qp + j * 8);
#pragma unroll
    for (int e = 0; e < 8; ++e) qf[j * 8 + e] = bf2f(v[e]);
  }

  // pass 1: logits
  float lg[9];
#pragma unroll
  for (int t = 0; t < 9; ++t) {
    const int ky = y + (t / 3 - 1) * dil;
    const int kx = x + (t % 3 - 1) * dil;
    float s = 0.f;
    if ((unsigned)ky < 128u && (unsigned)kx < 128u) {
      const unsigned short* kp = kvsrc + (size_t)((b << 14) + (ky << 7) + kx) * 1152 + 384 + co;
#pragma unroll
      for (int j = 0; j < 8; ++j) {
        s16x8 v = *(const s16x8*)(kp + j * 8);
#pragma unroll
        for (int e = 0; e < 8; ++e) s += qf[j * 8 + e] * bf2f(v[e]);
      }
    }
    lg[t] = s * 2.0f;   // SCALE = 2.0
  }

  // softmax over 9 (OOB logits are exactly 0, matching zero-padded gather)
  float mx = lg[0];
#pragma unroll
  for (int t = 1; t < 9; ++t) mx = fmaxf(mx, lg[t]);
  float w[9], den = 0.f;
#pragma unroll
  for (int t = 0; t < 9; ++t) { w[t] = __expf(lg[t] - mx); den += w[t]; }
  const float inv = 1.f / den;
#pragma unroll
  for (int t = 0; t < 9; ++t) w[t] *= inv;

  // pass 2: weighted V sum
  float out[64];
#pragma unroll
  for (int e = 0; e < 64; ++e) out[e] = 0.f;
#pragma unroll
  for (int t = 0; t < 9; ++t) {
    const int ky = y + (t / 3 - 1) * dil;
    const int kx = x + (t % 3 - 1) * dil;
    if ((unsigned)ky < 128u && (unsigned)kx < 128u) {
      const unsigned short* vp = kvsrc + (size_t)((b << 14) + (ky << 7) + kx) * 1152 + 768 + co;
#pragma unroll
      for (int j = 0; j < 8; ++j) {
        s16x8 v = *(const s16x8*)(vp + j * 8);
#pragma unroll
        for (int e = 0; e < 8; ++e) out[j * 8 + e] += w[t] * bf2f(v[e]);
      }
    }
  }

  // store bf16 att[pix][i*128 + h*64 + c]
  unsigned short* op = dst + (size_t)pix * 384 + co;
#pragma unroll
  for (int j = 0; j < 8; ++j) {
    s16x8 v;
#pragma unroll
    for (int e = 0; e < 8; ++e) v[e] = (short)f2b(out[j * 8 + e]);
    *(s16x8*)(op + j * 8) = v;
  }
}

// ---------------- launch ----------------
extern "C" void kernel_launch(void* const* d_in, const int* in_sizes, int n_in,
                              void* d_out, int out_size, void* d_ws, size_t ws_size,
                              hipStream_t stream) {
  const float* mov     = (const float*)d_in[0];
  const float* fixp    = (const float*)d_in[1];
  const float* Wm_qkv  = (const float*)d_in[2];
  const float* Wf_qkv  = (const float*)d_in[3];
  const float* Wm_proj = (const float*)d_in[4];
  const float* bm_proj = (const float*)d_in[5];
  const float* Wf_proj = (const float*)d_in[6];
  const float* bf_proj = (const float*)d_in[7];

  char* ws = (char*)d_ws;
  unsigned short* xm    = (unsigned short*)(ws);                  // 25,165,824 B
  unsigned short* xf    = (unsigned short*)(ws + 25165824);
  unsigned short* wqm   = (unsigned short*)(ws + 50331648);       // 884,736 B
  unsigned short* wqf   = (unsigned short*)(ws + 51216384);
  unsigned short* wpm   = (unsigned short*)(ws + 52101120);       // 294,912 B
  unsigned short* wpf   = (unsigned short*)(ws + 52396032);
  unsigned short* qkv_m = (unsigned short*)(ws + 52690944);       // 75,497,472 B
  unsigned short* qkv_f = (unsigned short*)(ws + 128188416);
  unsigned short* att_m = (unsigned short*)(ws + 203685888);      // 25,165,824 B
  unsigned short* att_f = (unsigned short*)(ws + 228851712);      // end: 254,017,536 B

  // converts
  cvt_f32_bf16<<<6144, 256, 0, stream>>>(mov,  xm, 1572864);
  cvt_f32_bf16<<<6144, 256, 0, stream>>>(fixp, xf, 1572864);
  cvt_f32_bf16<<<216, 256, 0, stream>>>(Wm_qkv, wqm, 55296);
  cvt_f32_bf16<<<216, 256, 0, stream>>>(Wf_qkv, wqf, 55296);
  cvt_f32_bf16<<<72, 256, 0, stream>>>(Wm_proj, wpm, 18432);
  cvt_f32_bf16<<<72, 256, 0, stream>>>(Wf_proj, wpf, 18432);

  // qkv projection: [32768 x 1152] = X[32768 x 384] * Wqkv[1152 x 384]^T
  gemm_bt<1152, false><<<dim3(256, 9, 2), 256, 0, stream>>>(
      xm, xf, wqm, wqf, qkv_m, qkv_f, nullptr, nullptr);

  // cross dilated attention
  dilate_attn<<<1536, 256, 0, stream>>>(qkv_m, qkv_f, att_m, att_f);

  // output projection + bias: f32 out
  gemm_bt<384, true><<<dim3(256, 3, 2), 256, 0, stream>>>(
      att_m, att_f, wpm, wpf,
      (float*)d_out, (float*)d_out + 12582912, bm_proj, bf_proj);
}

// Round 3
// 396.527 us; speedup vs baseline: 1.4162x; 1.4162x over previous
//
#include <hip/hip_runtime.h>
#include <hip/hip_bf16.h>

// Problem constants
#define PPIX 32768      // B*H*W = 2*128*128
#define K384 384        // C (GEMM K dim)

typedef __attribute__((ext_vector_type(8))) short s16x8;
typedef __attribute__((ext_vector_type(4))) float f32x4;

__device__ __forceinline__ float bf2f(short u) {
  union { unsigned int i; float f; } c;
  c.i = ((unsigned int)(unsigned short)u) << 16;
  return c.f;
}

__device__ __forceinline__ unsigned short f2b(float x) {
  union { float f; unsigned int i; } c; c.f = x;
  unsigned int u = c.i;
  return (unsigned short)((u + 0x7fffu + ((u >> 16) & 1u)) >> 16);  // RNE
}

// ---------------- f32 -> bf16 convert (8 elems/thread) ----------------
__global__ __launch_bounds__(256) void cvt_f32_bf16(const float* __restrict__ in,
                                                    unsigned short* __restrict__ out,
                                                    int n8) {
  int i = blockIdx.x * 256 + threadIdx.x;
  if (i >= n8) return;
  const float4* in4 = (const float4*)in;
  float4 a = in4[(size_t)i * 2], b = in4[(size_t)i * 2 + 1];
  s16x8 r;
  r[0] = (short)f2b(a.x); r[1] = (short)f2b(a.y); r[2] = (short)f2b(a.z); r[3] = (short)f2b(a.w);
  r[4] = (short)f2b(b.x); r[5] = (short)f2b(b.y); r[6] = (short)f2b(b.z); r[7] = (short)f2b(b.w);
  *(s16x8*)(out + (size_t)i * 8) = r;
}

// ---------------- bf16 MFMA GEMM: C[M,N] = A[M,K] * B[N,K]^T ----------------
// m97 structure: 128x128 tile, BK=64, 4 waves (2x2), global_load_lds width 16.
__device__ __forceinline__ void async_ld16(const void* g, void* l) {
  __builtin_amdgcn_global_load_lds(
      (const __attribute__((address_space(1))) unsigned int*)g,
      (__attribute__((address_space(3))) unsigned int*)l, 16, 0, 0);
}

template<int N, bool F32OUT>
__global__ __launch_bounds__(256) void gemm_bt(
    const unsigned short* __restrict__ A0, const unsigned short* __restrict__ A1,
    const unsigned short* __restrict__ B0, const unsigned short* __restrict__ B1,
    void* __restrict__ C0v, void* __restrict__ C1v,
    const float* __restrict__ bias0, const float* __restrict__ bias1) {
  const int bm = blockIdx.x, bn = blockIdx.y, bz = blockIdx.z;
  const unsigned short* A = bz ? A1 : A0;
  const unsigned short* Bm = bz ? B1 : B0;
  const int tid = threadIdx.x;
  const int wid = tid >> 6, lane = tid & 63;
  __shared__ unsigned short ldsA[128 * 64];
  __shared__ unsigned short ldsB[128 * 64];
  f32x4 acc[4][4] = {};
  const int wm = wid >> 1, wn = wid & 1;          // 2x2 wave grid, each wave 64x64
  const int srow = tid >> 3;                      // staging: 0..31 rows/issue
  const int scol = (tid & 7) * 8;                 // 8 bf16 (16B) per lane
  const int r = lane & 15, q2 = lane >> 4;

  for (int kt = 0; kt < K384 / 64; ++kt) {
    const int k0 = kt * 64;
#pragma unroll
    for (int j = 0; j < 4; ++j) {
      async_ld16(A + (size_t)(bm * 128 + j * 32 + srow) * K384 + k0 + scol,
                 (char*)ldsA + (j * 32 + wid * 8) * 128);
      async_ld16(Bm + (size_t)(bn * 128 + j * 32 + srow) * K384 + k0 + scol,
                 (char*)ldsB + (j * 32 + wid * 8) * 128);
    }
    __syncthreads();
#pragma unroll
    for (int ks = 0; ks < 2; ++ks) {
      s16x8 af[4], bf[4];
#pragma unroll
      for (int mi = 0; mi < 4; ++mi)
        af[mi] = *(const s16x8*)&ldsA[(wm * 64 + mi * 16 + r) * 64 + ks * 32 + q2 * 8];
#pragma unroll
      for (int ni = 0; ni < 4; ++ni)
        bf[ni] = *(const s16x8*)&ldsB[(wn * 64 + ni * 16 + r) * 64 + ks * 32 + q2 * 8];
#pragma unroll
      for (int mi = 0; mi < 4; ++mi)
#pragma unroll
        for (int ni = 0; ni < 4; ++ni)
          acc[mi][ni] = __builtin_amdgcn_mfma_f32_16x16x32_bf16(af[mi], bf[ni], acc[mi][ni], 0, 0, 0);
    }
    __syncthreads();
  }

  // Epilogue. C/D layout: col = lane&15, row = (lane>>4)*4 + reg  [m89-verified]
  if constexpr (F32OUT) {
    float* C = (float*)(bz ? C1v : C0v);
    const float* bias = bz ? bias1 : bias0;
#pragma unroll
    for (int mi = 0; mi < 4; ++mi)
#pragma unroll
      for (int ni = 0; ni < 4; ++ni) {
        const int gm = bm * 128 + wm * 64 + mi * 16 + q2 * 4;
        const int gn = bn * 128 + wn * 64 + ni * 16 + r;
        const float bv = bias[gn];
#pragma unroll
        for (int rr = 0; rr < 4; ++rr)
          C[(size_t)(gm + rr) * N + gn] = acc[mi][ni][rr] + bv;
      }
  } else {
    unsigned short* C = (unsigned short*)(bz ? C1v : C0v);
#pragma unroll
    for (int mi = 0; mi < 4; ++mi)
#pragma unroll
      for (int ni = 0; ni < 4; ++ni) {
        const int gm = bm * 128 + wm * 64 + mi * 16 + q2 * 4;
        const int gn = bn * 128 + wn * 64 + ni * 16 + r;
#pragma unroll
        for (int rr = 0; rr < 4; ++rr)
          C[(size_t)(gm + rr) * N + gn] = f2b(acc[mi][ni][rr]);
      }
  }
}

// ---------------- dilated 3x3 window attention, 8-lane-group version ----------------
// 8 lanes per (branch, pixel, dil, head); each lane owns 8 of 64 head channels.
// Group order: ((branch*3+i)*2+h)*32768 + pix  -> a wave = 8 consecutive pixels,
// same (branch,dil,head) => coalesced 16B/lane loads and stores.
// OOB taps: k=v=0 => logit contribution exactly 0 (matches zero-padded gather).
__global__ __launch_bounds__(256) void dilate_attn8(
    const unsigned short* __restrict__ qkv_m, const unsigned short* __restrict__ qkv_f,
    unsigned short* __restrict__ att_m, unsigned short* __restrict__ att_f) {
  const int t = blockIdx.x * 256 + threadIdx.x;   // 0 .. 3,145,727
  const int lane8 = t & 7;
  const int g = t >> 3;                           // 0 .. 393,215
  const int pix = g & 32767;
  const int rest = g >> 15;                       // 0..11 = branch*6 + i*2 + h
  const int branch = rest >= 6;                   // 0: q from fix, k/v from mov -> att_m
  const int ih = branch ? rest - 6 : rest;
  const int i = ih >> 1, h = ih & 1;
  const int dil = i + 1;
  const int x = pix & 127, y = (pix >> 7) & 127, b = pix >> 14;
  const unsigned short* qsrc  = branch ? qkv_m : qkv_f;
  const unsigned short* kvsrc = branch ? qkv_f : qkv_m;
  unsigned short* dst = branch ? att_f : att_m;
  const int co = i * 128 + h * 64 + lane8 * 8;

  // q: this lane's 8 channels -> f32
  float qf[8];
  {
    s16x8 v = *(const s16x8*)(qsrc + (size_t)pix * 1152 + co);
#pragma unroll
    for (int e = 0; e < 8; ++e) qf[e] = bf2f(v[e]);
  }

  float lg[9];
  s16x8 vk[9];
#pragma unroll
  for (int tt = 0; tt < 9; ++tt) {
    const int ky = y + (tt / 3 - 1) * dil;
    const int kx = x + (tt % 3 - 1) * dil;
    s16x8 kk;
#pragma unroll
    for (int e = 0; e < 8; ++e) { kk[e] = 0; vk[tt][e] = 0; }
    if ((unsigned)ky < 128u && (unsigned)kx < 128u) {
      const unsigned short* p = kvsrc + (size_t)((b << 14) + (ky << 7) + kx) * 1152 + co;
      kk = *(const s16x8*)(p + 384);
      vk[tt] = *(const s16x8*)(p + 768);
    }
    float s = 0.f;
#pragma unroll
    for (int e = 0; e < 8; ++e) s += qf[e] * bf2f(kk[e]);
    // 8-lane butterfly reduce: all 8 lanes get the full 64-ch dot
    s += __shfl_xor(s, 1, 8);
    s += __shfl_xor(s, 2, 8);
    s += __shfl_xor(s, 4, 8);
    lg[tt] = s * 2.0f;    // SCALE = 2.0; OOB => exactly 0
  }

  // softmax over 9 taps (redundant per lane — 9 values, trivial)
  float mx = lg[0];
#pragma unroll
  for (int tt = 1; tt < 9; ++tt) mx = fmaxf(mx, lg[tt]);
  float den = 0.f, w[9];
#pragma unroll
  for (int tt = 0; tt < 9; ++tt) { w[tt] = __expf(lg[tt] - mx); den += w[tt]; }
  const float inv = 1.f / den;

  // PV from cached V taps
  float out[8];
#pragma unroll
  for (int e = 0; e < 8; ++e) out[e] = 0.f;
#pragma unroll
  for (int tt = 0; tt < 9; ++tt) {
    const float wt = w[tt] * inv;
#pragma unroll
    for (int e = 0; e < 8; ++e) out[e] += wt * bf2f(vk[tt][e]);
  }

  // store this lane's 8 channels
  s16x8 r;
#pragma unroll
  for (int e = 0; e < 8; ++e) r[e] = (short)f2b(out[e]);
  *(s16x8*)(dst + (size_t)pix * 384 + co) = r;
}

// ---------------- launch ----------------
extern "C" void kernel_launch(void* const* d_in, const int* in_sizes, int n_in,
                              void* d_out, int out_size, void* d_ws, size_t ws_size,
                              hipStream_t stream) {
  const float* mov     = (const float*)d_in[0];
  const float* fixp    = (const float*)d_in[1];
  const float* Wm_qkv  = (const float*)d_in[2];
  const float* Wf_qkv  = (const float*)d_in[3];
  const float* Wm_proj = (const float*)d_in[4];
  const float* bm_proj = (const float*)d_in[5];
  const float* Wf_proj = (const float*)d_in[6];
  const float* bf_proj = (const float*)d_in[7];

  char* ws = (char*)d_ws;
  unsigned short* xm    = (unsigned short*)(ws);                  // 25,165,824 B
  unsigned short* xf    = (unsigned short*)(ws + 25165824);
  unsigned short* wqm   = (unsigned short*)(ws + 50331648);       // 884,736 B
  unsigned short* wqf   = (unsigned short*)(ws + 51216384);
  unsigned short* wpm   = (unsigned short*)(ws + 52101120);       // 294,912 B
  unsigned short* wpf   = (unsigned short*)(ws + 52396032);
  unsigned short* qkv_m = (unsigned short*)(ws + 52690944);       // 75,497,472 B
  unsigned short* qkv_f = (unsigned short*)(ws + 128188416);
  unsigned short* att_m = (unsigned short*)(ws + 203685888);      // 25,165,824 B
  unsigned short* att_f = (unsigned short*)(ws + 228851712);      // end: 254,017,536 B

  // converts
  cvt_f32_bf16<<<6144, 256, 0, stream>>>(mov,  xm, 1572864);
  cvt_f32_bf16<<<6144, 256, 0, stream>>>(fixp, xf, 1572864);
  cvt_f32_bf16<<<216, 256, 0, stream>>>(Wm_qkv, wqm, 55296);
  cvt_f32_bf16<<<216, 256, 0, stream>>>(Wf_qkv, wqf, 55296);
  cvt_f32_bf16<<<72, 256, 0, stream>>>(Wm_proj, wpm, 18432);
  cvt_f32_bf16<<<72, 256, 0, stream>>>(Wf_proj, wpf, 18432);

  // qkv projection: [32768 x 1152] = X[32768 x 384] * Wqkv[1152 x 384]^T
  gemm_bt<1152, false><<<dim3(256, 9, 2), 256, 0, stream>>>(
      xm, xf, wqm, wqf, qkv_m, qkv_f, nullptr, nullptr);

  // cross dilated attention: 393216 groups x 8 lanes = 3,145,728 threads
  dilate_attn8<<<12288, 256, 0, stream>>>(qkv_m, qkv_f, att_m, att_f);

  // output projection + bias: f32 out
  gemm_bt<384, true><<<dim3(256, 3, 2), 256, 0, stream>>>(
      att_m, att_f, wpm, wpf,
      (float*)d_out, (float*)d_out + 12582912, bm_proj, bf_proj);
}

// Round 5
// 389.728 us; speedup vs baseline: 1.4409x; 1.0174x over previous
//
#include <hip/hip_runtime.h>
#include <hip/hip_bf16.h>

#define PPIX 32768      // B*H*W = 2*128*128
#define K384 384        // C (GEMM K dim)

typedef __attribute__((ext_vector_type(8))) short s16x8;
typedef __attribute__((ext_vector_type(4))) float f32x4;

__device__ __forceinline__ float bf2f(short u) {
  union { unsigned int i; float f; } c;
  c.i = ((unsigned int)(unsigned short)u) << 16;
  return c.f;
}

__device__ __forceinline__ unsigned short f2b(float x) {
  union { float f; unsigned int i; } c; c.f = x;
  unsigned int u = c.i;
  return (unsigned short)((u + 0x7fffu + ((u >> 16) & 1u)) >> 16);  // RNE
}

// ---------------- fused f32 -> bf16 convert: 6 exact-sized segments ----------------
// seg blocks: mov 6144 | fix 6144 | Wm_qkv 216 | Wf_qkv 216 | Wm_proj 72 | Wf_proj 72
__global__ __launch_bounds__(256) void cvt_all(
    const float* __restrict__ s0, unsigned short* __restrict__ d0,
    const float* __restrict__ s1, unsigned short* __restrict__ d1,
    const float* __restrict__ s2, unsigned short* __restrict__ d2,
    const float* __restrict__ s3, unsigned short* __restrict__ d3,
    const float* __restrict__ s4, unsigned short* __restrict__ d4,
    const float* __restrict__ s5, unsigned short* __restrict__ d5) {
  int b = blockIdx.x;
  const float* s; unsigned short* d; int rb;
  if      (b < 6144)  { s = s0; d = d0; rb = b; }
  else if (b < 12288) { s = s1; d = d1; rb = b - 6144; }
  else if (b < 12504) { s = s2; d = d2; rb = b - 12288; }
  else if (b < 12720) { s = s3; d = d3; rb = b - 12504; }
  else if (b < 12792) { s = s4; d = d4; rb = b - 12720; }
  else                { s = s5; d = d5; rb = b - 12792; }
  int i = rb * 256 + threadIdx.x;
  const float4* in4 = (const float4*)s;
  float4 a = in4[(size_t)i * 2], c4 = in4[(size_t)i * 2 + 1];
  s16x8 r;
  r[0] = (short)f2b(a.x);  r[1] = (short)f2b(a.y);  r[2] = (short)f2b(a.z);  r[3] = (short)f2b(a.w);
  r[4] = (short)f2b(c4.x); r[5] = (short)f2b(c4.y); r[6] = (short)f2b(c4.z); r[7] = (short)f2b(c4.w);
  *(s16x8*)(d + (size_t)i * 8) = r;
}

// ---------------- bf16 MFMA GEMM: C[M,N] = A[M,K] * B[N,K]^T ----------------
// m97 structure: 128x128 tile, BK=64, 4 waves (2x2), global_load_lds width 16.
// Epilogue: per-wave LDS repack (8 KB slice) -> coalesced 16B/lane stores.
__device__ __forceinline__ void async_ld16(const void* g, void* l) {
  __builtin_amdgcn_global_load_lds(
      (const __attribute__((address_space(1))) unsigned int*)g,
      (__attribute__((address_space(3))) unsigned int*)l, 16, 0, 0);
}

template<int N, bool F32OUT>
__global__ __launch_bounds__(256) void gemm_bt(
    const unsigned short* __restrict__ A0, const unsigned short* __restrict__ A1,
    const unsigned short* __restrict__ B0, const unsigned short* __restrict__ B1,
    void* __restrict__ C0v, void* __restrict__ C1v,
    const float* __restrict__ bias0, const float* __restrict__ bias1) {
  const int bm = blockIdx.x, bn = blockIdx.y, bz = blockIdx.z;
  const unsigned short* A = bz ? A1 : A0;
  const unsigned short* Bm = bz ? B1 : B0;
  const int tid = threadIdx.x;
  const int wid = tid >> 6, lane = tid & 63;
  __shared__ unsigned short lds[2][128 * 64];
  unsigned short* ldsA = lds[0];
  unsigned short* ldsB = lds[1];
  f32x4 acc[4][4] = {};
  const int wm = wid >> 1, wn = wid & 1;          // 2x2 wave grid, each wave 64x64
  const int srow = tid >> 3;                      // staging: 0..31 rows/issue
  const int scol = (tid & 7) * 8;                 // 8 bf16 (16B) per lane
  const int r = lane & 15, q2 = lane >> 4;

  for (int kt = 0; kt < K384 / 64; ++kt) {
    const int k0 = kt * 64;
#pragma unroll
    for (int j = 0; j < 4; ++j) {
      async_ld16(A + (size_t)(bm * 128 + j * 32 + srow) * K384 + k0 + scol,
                 (char*)ldsA + (j * 32 + wid * 8) * 128);
      async_ld16(Bm + (size_t)(bn * 128 + j * 32 + srow) * K384 + k0 + scol,
                 (char*)ldsB + (j * 32 + wid * 8) * 128);
    }
    __syncthreads();
#pragma unroll
    for (int ks = 0; ks < 2; ++ks) {
      s16x8 af[4], bf[4];
#pragma unroll
      for (int mi = 0; mi < 4; ++mi)
        af[mi] = *(const s16x8*)&ldsA[(wm * 64 + mi * 16 + r) * 64 + ks * 32 + q2 * 8];
#pragma unroll
      for (int ni = 0; ni < 4; ++ni)
        bf[ni] = *(const s16x8*)&ldsB[(wn * 64 + ni * 16 + r) * 64 + ks * 32 + q2 * 8];
#pragma unroll
      for (int mi = 0; mi < 4; ++mi)
#pragma unroll
        for (int ni = 0; ni < 4; ++ni)
          acc[mi][ni] = __builtin_amdgcn_mfma_f32_16x16x32_bf16(af[mi], bf[ni], acc[mi][ni], 0, 0, 0);
    }
    __syncthreads();   // last one also protects LDS reuse by the epilogue
  }

  // C/D frag layout: col = lane&15, row = (lane>>4)*4 + reg  [m89-verified]
  // Per-wave private 8 KB LDS slice (waves 0,1 in lds[0]; 2,3 in lds[1]).
  unsigned short* slice = &lds[wid >> 1][(wid & 1) * 4096];

  if constexpr (!F32OUT) {
    unsigned short* C = (unsigned short*)(bz ? C1v : C0v);
#pragma unroll
    for (int mi = 0; mi < 4; ++mi)
#pragma unroll
      for (int ni = 0; ni < 4; ++ni)
#pragma unroll
        for (int rr = 0; rr < 4; ++rr)
          slice[(mi * 16 + q2 * 4 + rr) * 64 + ni * 16 + r] = f2b(acc[mi][ni][rr]);
    asm volatile("s_waitcnt lgkmcnt(0)" ::: "memory");
    const size_t cbase = (size_t)(bm * 128 + wm * 64) * N + bn * 128 + wn * 64;
#pragma unroll
    for (int c = 0; c < 8; ++c) {
      const int gr = c * 8 + (lane >> 3), gc = (lane & 7) * 8;
      s16x8 v = *(const s16x8*)&slice[c * 512 + lane * 8];
      *(s16x8*)&C[cbase + (size_t)gr * N + gc] = v;
    }
  } else {
    float* C = (float*)(bz ? C1v : C0v);
    const float* bias = bz ? bias1 : bias0;
    float* sliceF = (float*)slice;   // 2048 f32 = 8 KB, half-quadrant per pass
#pragma unroll
    for (int p = 0; p < 2; ++p) {
      asm volatile("s_waitcnt lgkmcnt(0)" ::: "memory");  // prior pass reads drained
#pragma unroll
      for (int mi2 = 0; mi2 < 2; ++mi2) {
        const int mi = p * 2 + mi2;
#pragma unroll
        for (int ni = 0; ni < 4; ++ni) {
          const float bv = bias[bn * 128 + wn * 64 + ni * 16 + r];
#pragma unroll
          for (int rr = 0; rr < 4; ++rr)
            sliceF[(mi2 * 16 + q2 * 4 + rr) * 64 + ni * 16 + r] = acc[mi][ni][rr] + bv;
        }
      }
      asm volatile("s_waitcnt lgkmcnt(0)" ::: "memory");
#pragma unroll
      for (int c = 0; c < 8; ++c) {
        const int rr2 = c * 4 + (lane >> 4), gc = (lane & 15) * 4;
        float4 v = *(const float4*)&sliceF[rr2 * 64 + gc];
        *(float4*)&C[(size_t)(bm * 128 + wm * 64 + p * 32 + rr2) * N + bn * 128 + wn * 64 + gc] = v;
      }
    }
  }
}

// ---------------- dilated 3x3 window attention, 8-lane-group version ----------------
// 8 lanes per (branch, pixel, dil, head); each lane owns 8 of 64 head channels.
// OOB taps: k=v=0 => logit contribution exactly 0 (matches zero-padded gather).
__global__ __launch_bounds__(256) void dilate_attn8(
    const unsigned short* __restrict__ qkv_m, const unsigned short* __restrict__ qkv_f,
    unsigned short* __restrict__ att_m, unsigned short* __restrict__ att_f) {
  const int t = blockIdx.x * 256 + threadIdx.x;   // 0 .. 3,145,727
  const int lane8 = t & 7;
  const int g = t >> 3;                           // 0 .. 393,215
  const int pix = g & 32767;
  const int rest = g >> 15;                       // 0..11 = branch*6 + i*2 + h
  const int branch = rest >= 6;                   // 0: q from fix, k/v from mov -> att_m
  const int ih = branch ? rest - 6 : rest;
  const int i = ih >> 1, h = ih & 1;
  const int dil = i + 1;
  const int x = pix & 127, y = (pix >> 7) & 127, b = pix >> 14;
  const unsigned short* qsrc  = branch ? qkv_m : qkv_f;
  const unsigned short* kvsrc = branch ? qkv_f : qkv_m;
  unsigned short* dst = branch ? att_f : att_m;
  const int co = i * 128 + h * 64 + lane8 * 8;

  float qf[8];
  {
    s16x8 v = *(const s16x8*)(qsrc + (size_t)pix * 1152 + co);
#pragma unroll
    for (int e = 0; e < 8; ++e) qf[e] = bf2f(v[e]);
  }

  float lg[9];
  s16x8 vk[9];
#pragma unroll
  for (int tt = 0; tt < 9; ++tt) {
    const int ky = y + (tt / 3 - 1) * dil;
    const int kx = x + (tt % 3 - 1) * dil;
    s16x8 kk;
#pragma unroll
    for (int e = 0; e < 8; ++e) { kk[e] = 0; vk[tt][e] = 0; }
    if ((unsigned)ky < 128u && (unsigned)kx < 128u) {
      const unsigned short* p = kvsrc + (size_t)((b << 14) + (ky << 7) + kx) * 1152 + co;
      kk = *(const s16x8*)(p + 384);
      vk[tt] = *(const s16x8*)(p + 768);
    }
    float s = 0.f;
#pragma unroll
    for (int e = 0; e < 8; ++e) s += qf[e] * bf2f(kk[e]);
    s += __shfl_xor(s, 1, 8);
    s += __shfl_xor(s, 2, 8);
    s += __shfl_xor(s, 4, 8);
    lg[tt] = s * 2.0f;    // SCALE = 2.0; OOB => exactly 0
  }

  float mx = lg[0];
#pragma unroll
  for (int tt = 1; tt < 9; ++tt) mx = fmaxf(mx, lg[tt]);
  float den = 0.f, w[9];
#pragma unroll
  for (int tt = 0; tt < 9; ++tt) { w[tt] = __expf(lg[tt] - mx); den += w[tt]; }
  const float inv = 1.f / den;

  float out[8];
#pragma unroll
  for (int e = 0; e < 8; ++e) out[e] = 0.f;
#pragma unroll
  for (int tt = 0; tt < 9; ++tt) {
    const float wt = w[tt] * inv;
#pragma unroll
    for (int e = 0; e < 8; ++e) out[e] += wt * bf2f(vk[tt][e]);
  }

  s16x8 rv;
#pragma unroll
  for (int e = 0; e < 8; ++e) rv[e] = (short)f2b(out[e]);
  *(s16x8*)(dst + (size_t)pix * 384 + co) = rv;
}

// ---------------- launch ----------------
extern "C" void kernel_launch(void* const* d_in, const int* in_sizes, int n_in,
                              void* d_out, int out_size, void* d_ws, size_t ws_size,
                              hipStream_t stream) {
  const float* mov     = (const float*)d_in[0];
  const float* fixp    = (const float*)d_in[1];
  const float* Wm_qkv  = (const float*)d_in[2];
  const float* Wf_qkv  = (const float*)d_in[3];
  const float* Wm_proj = (const float*)d_in[4];
  const float* bm_proj = (const float*)d_in[5];
  const float* Wf_proj = (const float*)d_in[6];
  const float* bf_proj = (const float*)d_in[7];

  char* ws = (char*)d_ws;
  unsigned short* xm    = (unsigned short*)(ws);                  // 25,165,824 B
  unsigned short* xf    = (unsigned short*)(ws + 25165824);
  unsigned short* wqm   = (unsigned short*)(ws + 50331648);       // 884,736 B
  unsigned short* wqf   = (unsigned short*)(ws + 51216384);
  unsigned short* wpm   = (unsigned short*)(ws + 52101120);       // 294,912 B
  unsigned short* wpf   = (unsigned short*)(ws + 52396032);
  unsigned short* qkv_m = (unsigned short*)(ws + 52690944);       // 75,497,472 B
  unsigned short* qkv_f = (unsigned short*)(ws + 128188416);
  unsigned short* att_m = (unsigned short*)(ws + 203685888);      // 25,165,824 B
  unsigned short* att_f = (unsigned short*)(ws + 228851712);      // end: 254,017,536 B

  // all f32->bf16 converts in one launch (exact-sized segments)
  cvt_all<<<12864, 256, 0, stream>>>(mov, xm, fixp, xf, Wm_qkv, wqm,
                                     Wf_qkv, wqf, Wm_proj, wpm, Wf_proj, wpf);

  // qkv projection: [32768 x 1152] = X[32768 x 384] * Wqkv[1152 x 384]^T
  gemm_bt<1152, false><<<dim3(256, 9, 2), 256, 0, stream>>>(
      xm, xf, wqm, wqf, qkv_m, qkv_f, nullptr, nullptr);

  // cross dilated attention: 393216 groups x 8 lanes
  dilate_attn8<<<12288, 256, 0, stream>>>(qkv_m, qkv_f, att_m, att_f);

  // output projection + bias: f32 out
  gemm_bt<384, true><<<dim3(256, 3, 2), 256, 0, stream>>>(
      att_m, att_f, wpm, wpf,
      (float*)d_out, (float*)d_out + 12582912, bm_proj, bf_proj);
}

// Round 7
// 363.345 us; speedup vs baseline: 1.5455x; 1.0726x over previous
//
#include <hip/hip_runtime.h>
#include <hip/hip_bf16.h>

#define K384 384        // C (GEMM K dim)
#define NP   1280       // padded qkv row stride (5 x 256)

typedef __attribute__((ext_vector_type(8))) short s16x8;
typedef __attribute__((ext_vector_type(4))) float f32x4;

__device__ __forceinline__ float bf2f(short u) {
  union { unsigned int i; float f; } c;
  c.i = ((unsigned int)(unsigned short)u) << 16;
  return c.f;
}

__device__ __forceinline__ unsigned short f2b(float x) {
  union { float f; unsigned int i; } c; c.f = x;
  unsigned int u = c.i;
  return (unsigned short)((u + 0x7fffu + ((u >> 16) & 1u)) >> 16);  // RNE
}

// ---------------- fused f32 -> bf16 convert + weight-pad zero-fill ----------------
// blocks: mov 6144 | fix 6144 | WqM 216 | WqF 216 | WpM 72 | WpF 72 | zeroM 24 | zeroF 24
__global__ __launch_bounds__(256) void cvt_all(
    const float* __restrict__ s0, unsigned short* __restrict__ d0,
    const float* __restrict__ s1, unsigned short* __restrict__ d1,
    const float* __restrict__ s2, unsigned short* __restrict__ d2,
    const float* __restrict__ s3, unsigned short* __restrict__ d3,
    const float* __restrict__ s4, unsigned short* __restrict__ d4,
    const float* __restrict__ s5, unsigned short* __restrict__ d5) {
  int b = blockIdx.x;
  if (b >= 12864) {  // zero-fill pad rows 1152..1279 of wq buffers
    unsigned short* d = (b < 12888) ? d2 : d3;
    int i = (b - ((b < 12888) ? 12864 : 12888)) * 256 + threadIdx.x;  // 0..6143
    s16x8 z = {};
    *(s16x8*)(d + 442368 + (size_t)i * 8) = z;
    return;
  }
  const float* s; unsigned short* d; int rb;
  if      (b < 6144)  { s = s0; d = d0; rb = b; }
  else if (b < 12288) { s = s1; d = d1; rb = b - 6144; }
  else if (b < 12504) { s = s2; d = d2; rb = b - 12288; }
  else if (b < 12720) { s = s3; d = d3; rb = b - 12504; }
  else if (b < 12792) { s = s4; d = d4; rb = b - 12720; }
  else                { s = s5; d = d5; rb = b - 12792; }
  int i = rb * 256 + threadIdx.x;
  const float4* in4 = (const float4*)s;
  float4 a = in4[(size_t)i * 2], c4 = in4[(size_t)i * 2 + 1];
  s16x8 r;
  r[0] = (short)f2b(a.x);  r[1] = (short)f2b(a.y);  r[2] = (short)f2b(a.z);  r[3] = (short)f2b(a.w);
  r[4] = (short)f2b(c4.x); r[5] = (short)f2b(c4.y); r[6] = (short)f2b(c4.z); r[7] = (short)f2b(c4.w);
  *(s16x8*)(d + (size_t)i * 8) = r;
}

__device__ __forceinline__ void async_ld16(const void* g, void* l) {
  __builtin_amdgcn_global_load_lds(
      (const __attribute__((address_space(1))) unsigned int*)g,
      (__attribute__((address_space(3))) unsigned int*)l, 16, 0, 0);
}

// ---------------- QKV GEMM: 256x256 tile, BK=64, 8 waves, dbuf counted-vmcnt ----------------
// C[M,NP] = A[M,K] * B[NP,K]^T   (B zero-padded rows 1152..1279)
// LDS 128 KB: lA[2] at ushort 0, lB[2] at ushort 32768. T2 swizzle: source chunk
// pre-XORed by (row&7), linear LDS dest (global_load_lds), XOR on ds_read.
__global__ __launch_bounds__(512, 2) void gemm_qkv256(
    const unsigned short* __restrict__ A0, const unsigned short* __restrict__ A1,
    const unsigned short* __restrict__ B0, const unsigned short* __restrict__ B1,
    unsigned short* __restrict__ C0, unsigned short* __restrict__ C1) {
  const int bm = blockIdx.x, bn = blockIdx.y, bz = blockIdx.z;
  const unsigned short* A = bz ? A1 : A0;
  const unsigned short* B = bz ? B1 : B0;
  unsigned short* C = bz ? C1 : C0;
  const int tid = threadIdx.x;
  const int w = tid >> 6, lane = tid & 63;
  const int wm = w >> 2, wn = w & 3;            // 2 x 4 wave grid; per-wave 128x64 out
  const int r_ = lane & 15, q2 = lane >> 4;
  __shared__ unsigned short L[65536];           // 128 KB

  f32x4 acc[8][4] = {};

  const int rlo = (tid >> 3) & 7;               // lane>>3 (row low bits within 8-row stripe)
  const int sc = ((lane & 7) ^ rlo) * 8;        // pre-swizzled source chunk (ushort)
  const size_t arow0 = (size_t)bm * 256;
  const size_t brow0 = (size_t)bn * 256;

  auto STAGE = [&](int kt, int b01) {
    const int k0 = kt * 64;
#pragma unroll
    for (int j = 0; j < 4; ++j) {
      const int rr = j * 64 + w * 8;            // wave-uniform row base
      async_ld16(A + (arow0 + rr + rlo) * K384 + k0 + sc,
                 (char*)L + (size_t)(b01 * 16384 + rr * 64) * 2);
      async_ld16(B + (brow0 + rr + rlo) * K384 + k0 + sc,
                 (char*)L + (size_t)(32768 + b01 * 16384 + rr * 64) * 2);
    }
  };

  auto COMPUTE = [&](int b01) {
    const unsigned short* bufA = L + b01 * 16384;
    const unsigned short* bufB = L + 32768 + b01 * 16384;
#pragma unroll
    for (int ks = 0; ks < 2; ++ks) {
      s16x8 af[8], bf[4];
#pragma unroll
      for (int mi = 0; mi < 8; ++mi) {
        const int row = wm * 128 + mi * 16 + r_;
        const int c = (ks * 4 + q2) ^ (r_ & 7);   // read-side un-swizzle
        af[mi] = *(const s16x8*)&bufA[row * 64 + c * 8];
      }
#pragma unroll
      for (int ni = 0; ni < 4; ++ni) {
        const int row = wn * 64 + ni * 16 + r_;
        const int c = (ks * 4 + q2) ^ (r_ & 7);
        bf[ni] = *(const s16x8*)&bufB[row * 64 + c * 8];
      }
#pragma unroll
      for (int mi = 0; mi < 8; ++mi)
#pragma unroll
        for (int ni = 0; ni < 4; ++ni)
          acc[mi][ni] = __builtin_amdgcn_mfma_f32_16x16x32_bf16(af[mi], bf[ni], acc[mi][ni], 0, 0, 0);
    }
  };

  STAGE(0, 0);
  STAGE(1, 1);        // 16 loads/thread in flight
#pragma unroll
  for (int kt = 0; kt < 6; ++kt) {
    if (kt < 5) { asm volatile("s_waitcnt vmcnt(8)" ::: "memory"); }   // tile kt landed
    else        { asm volatile("s_waitcnt vmcnt(0)" ::: "memory"); }
    __builtin_amdgcn_s_barrier();
    __builtin_amdgcn_sched_barrier(0);
    COMPUTE(kt & 1);
    __builtin_amdgcn_sched_barrier(0);
    __builtin_amdgcn_s_barrier();
    __builtin_amdgcn_sched_barrier(0);
    if (kt + 2 < 6) STAGE(kt + 2, kt & 1);      // refill freed buffer
  }
  __builtin_amdgcn_s_barrier();                 // before LDS reuse by epilogue

  // Epilogue: wave-private 16 KB slice repack -> 16B/lane coalesced stores.
  unsigned short* slice = L + w * 8192;
#pragma unroll
  for (int mi = 0; mi < 8; ++mi)
#pragma unroll
    for (int ni = 0; ni < 4; ++ni)
#pragma unroll
      for (int rr2 = 0; rr2 < 4; ++rr2)
        slice[(mi * 16 + q2 * 4 + rr2) * 64 + ni * 16 + r_] = f2b(acc[mi][ni][rr2]);
  asm volatile("s_waitcnt lgkmcnt(0)" ::: "memory");
  __builtin_amdgcn_sched_barrier(0);
  const size_t crow0 = (size_t)(bm * 256 + wm * 128);
  const int ccol0 = bn * 256 + wn * 64;
#pragma unroll
  for (int c = 0; c < 16; ++c) {
    s16x8 v = *(const s16x8*)&slice[c * 512 + lane * 8];
    *(s16x8*)&C[(crow0 + c * 8 + (lane >> 3)) * NP + ccol0 + (lane & 7) * 8] = v;
  }
}

// ---------------- proj GEMM (old m97 structure, f32 out + bias) ----------------
template<int N>
__global__ __launch_bounds__(256) void gemm_proj(
    const unsigned short* __restrict__ A0, const unsigned short* __restrict__ A1,
    const unsigned short* __restrict__ B0, const unsigned short* __restrict__ B1,
    float* __restrict__ C0, float* __restrict__ C1,
    const float* __restrict__ bias0, const float* __restrict__ bias1) {
  const int bm = blockIdx.x, bn = blockIdx.y, bz = blockIdx.z;
  const unsigned short* A = bz ? A1 : A0;
  const unsigned short* Bm = bz ? B1 : B0;
  const int tid = threadIdx.x;
  const int wid = tid >> 6, lane = tid & 63;
  __shared__ unsigned short lds[2][128 * 64];
  unsigned short* ldsA = lds[0];
  unsigned short* ldsB = lds[1];
  f32x4 acc[4][4] = {};
  const int wm = wid >> 1, wn = wid & 1;
  const int srow = tid >> 3;
  const int scol = (tid & 7) * 8;
  const int r = lane & 15, q2 = lane >> 4;

  for (int kt = 0; kt < K384 / 64; ++kt) {
    const int k0 = kt * 64;
#pragma unroll
    for (int j = 0; j < 4; ++j) {
      async_ld16(A + (size_t)(bm * 128 + j * 32 + srow) * K384 + k0 + scol,
                 (char*)ldsA + (j * 32 + wid * 8) * 128);
      async_ld16(Bm + (size_t)(bn * 128 + j * 32 + srow) * K384 + k0 + scol,
                 (char*)ldsB + (j * 32 + wid * 8) * 128);
    }
    __syncthreads();
#pragma unroll
    for (int ks = 0; ks < 2; ++ks) {
      s16x8 af[4], bf[4];
#pragma unroll
      for (int mi = 0; mi < 4; ++mi)
        af[mi] = *(const s16x8*)&ldsA[(wm * 64 + mi * 16 + r) * 64 + ks * 32 + q2 * 8];
#pragma unroll
      for (int ni = 0; ni < 4; ++ni)
        bf[ni] = *(const s16x8*)&ldsB[(wn * 64 + ni * 16 + r) * 64 + ks * 32 + q2 * 8];
#pragma unroll
      for (int mi = 0; mi < 4; ++mi)
#pragma unroll
        for (int ni = 0; ni < 4; ++ni)
          acc[mi][ni] = __builtin_amdgcn_mfma_f32_16x16x32_bf16(af[mi], bf[ni], acc[mi][ni], 0, 0, 0);
    }
    __syncthreads();
  }

  float* C = bz ? C1 : C0;
  const float* bias = bz ? bias1 : bias0;
  unsigned short* slice = &lds[wid >> 1][(wid & 1) * 4096];
  float* sliceF = (float*)slice;
#pragma unroll
  for (int p = 0; p < 2; ++p) {
    asm volatile("s_waitcnt lgkmcnt(0)" ::: "memory");
#pragma unroll
    for (int mi2 = 0; mi2 < 2; ++mi2) {
      const int mi = p * 2 + mi2;
#pragma unroll
      for (int ni = 0; ni < 4; ++ni) {
        const float bv = bias[bn * 128 + wn * 64 + ni * 16 + r];
#pragma unroll
        for (int rr = 0; rr < 4; ++rr)
          sliceF[(mi2 * 16 + q2 * 4 + rr) * 64 + ni * 16 + r] = acc[mi][ni][rr] + bv;
      }
    }
    asm volatile("s_waitcnt lgkmcnt(0)" ::: "memory");
#pragma unroll
    for (int c = 0; c < 8; ++c) {
      const int rr2 = c * 4 + (lane >> 4), gc = (lane & 15) * 4;
      float4 v = *(const float4*)&sliceF[rr2 * 64 + gc];
      *(float4*)&C[(size_t)(bm * 128 + wm * 64 + p * 32 + rr2) * N + bn * 128 + wn * 64 + gc] = v;
    }
  }
}

// ---------------- dilated 3x3 window attention, 8-lane-group version ----------------
__global__ __launch_bounds__(256) void dilate_attn8(
    const unsigned short* __restrict__ qkv_m, const unsigned short* __restrict__ qkv_f,
    unsigned short* __restrict__ att_m, unsigned short* __restrict__ att_f) {
  const int t = blockIdx.x * 256 + threadIdx.x;
  const int lane8 = t & 7;
  const int g = t >> 3;
  const int pix = g & 32767;
  const int rest = g >> 15;                     // 0..11 = branch*6 + i*2 + h
  const int branch = rest >= 6;
  const int ih = branch ? rest - 6 : rest;
  const int i = ih >> 1, h = ih & 1;
  const int dil = i + 1;
  const int x = pix & 127, y = (pix >> 7) & 127, b = pix >> 14;
  const unsigned short* qsrc  = branch ? qkv_m : qkv_f;
  const unsigned short* kvsrc = branch ? qkv_f : qkv_m;
  unsigned short* dst = branch ? att_f : att_m;
  const int co = i * 128 + h * 64 + lane8 * 8;

  float qf[8];
  {
    s16x8 v = *(const s16x8*)(qsrc + (size_t)pix * NP + co);
#pragma unroll
    for (int e = 0; e < 8; ++e) qf[e] = bf2f(v[e]);
  }

  float lg[9];
  s16x8 vk[9];
#pragma unroll
  for (int tt = 0; tt < 9; ++tt) {
    const int ky = y + (tt / 3 - 1) * dil;
    const int kx = x + (tt % 3 - 1) * dil;
    s16x8 kk;
#pragma unroll
    for (int e = 0; e < 8; ++e) { kk[e] = 0; vk[tt][e] = 0; }
    if ((unsigned)ky < 128u && (unsigned)kx < 128u) {
      const unsigned short* p = kvsrc + (size_t)((b << 14) + (ky << 7) + kx) * NP + co;
      kk = *(const s16x8*)(p + 384);
      vk[tt] = *(const s16x8*)(p + 768);
    }
    float s = 0.f;
#pragma unroll
    for (int e = 0; e < 8; ++e) s += qf[e] * bf2f(kk[e]);
    s += __shfl_xor(s, 1, 8);
    s += __shfl_xor(s, 2, 8);
    s += __shfl_xor(s, 4, 8);
    lg[tt] = s * 2.0f;    // SCALE = 2.0; OOB => exactly 0
  }

  float mx = lg[0];
#pragma unroll
  for (int tt = 1; tt < 9; ++tt) mx = fmaxf(mx, lg[tt]);
  float den = 0.f, wgt[9];
#pragma unroll
  for (int tt = 0; tt < 9; ++tt) { wgt[tt] = __expf(lg[tt] - mx); den += wgt[tt]; }
  const float inv = 1.f / den;

  float out[8];
#pragma unroll
  for (int e = 0; e < 8; ++e) out[e] = 0.f;
#pragma unroll
  for (int tt = 0; tt < 9; ++tt) {
    const float wt = wgt[tt] * inv;
#pragma unroll
    for (int e = 0; e < 8; ++e) out[e] += wt * bf2f(vk[tt][e]);
  }

  s16x8 rv;
#pragma unroll
  for (int e = 0; e < 8; ++e) rv[e] = (short)f2b(out[e]);
  *(s16x8*)(dst + (size_t)pix * 384 + co) = rv;
}

// ---------------- launch ----------------
extern "C" void kernel_launch(void* const* d_in, const int* in_sizes, int n_in,
                              void* d_out, int out_size, void* d_ws, size_t ws_size,
                              hipStream_t stream) {
  const float* mov     = (const float*)d_in[0];
  const float* fixp    = (const float*)d_in[1];
  const float* Wm_qkv  = (const float*)d_in[2];
  const float* Wf_qkv  = (const float*)d_in[3];
  const float* Wm_proj = (const float*)d_in[4];
  const float* bm_proj = (const float*)d_in[5];
  const float* Wf_proj = (const float*)d_in[6];
  const float* bf_proj = (const float*)d_in[7];

  char* ws = (char*)d_ws;
  // x and att SHARE storage: x dead after QKV GEMM, att written after.
  unsigned short* xm    = (unsigned short*)(ws);                  // 25,165,824 B
  unsigned short* xf    = (unsigned short*)(ws + 25165824);       // 25,165,824 B
  unsigned short* att_m = xm;                                     // reuse
  unsigned short* att_f = xf;                                     // reuse
  unsigned short* wqm   = (unsigned short*)(ws + 50331648);       // 1280x384x2 = 983,040 B
  unsigned short* wqf   = (unsigned short*)(ws + 51314688);       // 983,040 B
  unsigned short* wpm   = (unsigned short*)(ws + 52297728);       // 294,912 B
  unsigned short* wpf   = (unsigned short*)(ws + 52592640);       // 294,912 B
  unsigned short* qkv_m = (unsigned short*)(ws + 52887552);       // 32768x1280x2 = 83,886,080 B
  unsigned short* qkv_f = (unsigned short*)(ws + 136773632);      // 83,886,080 B -> end 220,659,712

  cvt_all<<<12912, 256, 0, stream>>>(mov, xm, fixp, xf, Wm_qkv, wqm,
                                     Wf_qkv, wqf, Wm_proj, wpm, Wf_proj, wpf);

  // qkv projection: [32768 x 1280] = X[32768 x 384] * Wqkv_pad[1280 x 384]^T
  gemm_qkv256<<<dim3(128, 5, 2), 512, 0, stream>>>(xm, xf, wqm, wqf, qkv_m, qkv_f);

  // cross dilated attention (reads stride-NP qkv, writes stride-384 att over x)
  dilate_attn8<<<12288, 256, 0, stream>>>(qkv_m, qkv_f, att_m, att_f);

  // output projection + bias: f32 out
  gemm_proj<384><<<dim3(256, 3, 2), 256, 0, stream>>>(
      att_m, att_f, wpm, wpf,
      (float*)d_out, (float*)d_out + 12582912, bm_proj, bf_proj);
}